// Round 5
// baseline (367.267 us; speedup 1.0000x reference)
//
#include <hip/hip_runtime.h>
#include <hip/hip_fp16.h>

// TGCN forward, algebraically reduced (H0 = 0 => R/Wr dead, Z*H = 0):
//   deg[d] = #in-edges of d ; dinv = rsqrt(deg+1)
//   xs[s]  = fp16( x[s] * dinv[s] )
//   agg[d] = bf16( dinv[d] * ( sum_{e: dst=d} xs[src] + xs[d]*dinv[d] ) )
//   M = [Wz@Lzw_top | Wh@Lhw_top]  (64x512, bf16, MFMA B-layout), cb = bias fold
//   out = softmax(relu((1-Z)*Ht) @ Wo + bo)
//
// R1 -> R2: atomic scatter (2700us) -> CSR build + register gather.
// R3 -> R4: scatter write amp -> 2-level bucket sort (793 -> 455us).
// R7 -> R8: node GEMM -> mfma_f32_16x16x32_bf16 (412 -> off top-5).
// R13 -> R14: global-cursor atomics -> deterministic offsets (315 -> 304).
// R14 -> R15: epilogue fp32 divides -> v_rcp_f32 (304 -> 275.7).
// R15 -> R16: 9 -> 6 launches. NEUTRAL: graph capture amortizes launches.
// R16 -> R17: LDS ds_add_f32 per-edge accumulation. DISASTER (1339us):
// serialized dependent LDS atomics. Lesson: LDS atomics = occasional only.
// R17 -> R18: LDS-resident csr (good, ~-25us) but deg via 3.2M scattered
// global atomics = 130us (device-scope atomics -> memory-side round trip).
// R18 -> R19: deg via per-bucket LDS histogram in prep. 264.5us. bucket_
// gather = 62.2 (random-xs floor 53.5 + sort ~9). Remaining 202us is spread
// over 6 sub-62us kernels; bottom-up model says node_mfma + its aggb HBM
// round-trip is the bulk (~120us incl. gaps).
// R19 -> R20: fuse node_mfma INTO bucket_gather. SHIFT 8->7 (one block per
// 128-node bucket, no half-discard read). agg rows land in LDS in MFMA
// A-fragment order ([st][kc][quad][nidx], wave-private writes, contiguous
// conflict-free reads); per-block MFMA + gate math + head (width-16 shfl
// reduce + occasional LDS f32 atomics into part[128][4]) + softmax write
// out directly. aggb array and node_mfma kernel deleted (-25.3MB HBM,
// -1 kernel). cg-split r-loops keep VGPR ~70; launch_bounds(512,6) for
// 3 blocks/CU (LDS ~44.5KB); grid 782 ~= one co-resident pass (768).

#define SHIFT 7
#define NPB   128          // nodes per bucket (=1<<SHIFT)
#define BMAX  1024         // max buckets (n <= 131072 for 17-bit src packing)
#define TILE  8192         // edges per tile (hist/scatter blocks)
#define MBBLK 64           // fused build_m blocks (512 j-cols / 8 per block)
#define CAP   6144         // LDS csr entries per bucket (mean 4096, sd 64)

typedef __attribute__((ext_vector_type(8))) short short8;
typedef __attribute__((ext_vector_type(4))) float floatx4;

__device__ __forceinline__ ushort f2b(float f) {   // fp32 -> bf16 RNE
    union { float f; unsigned u; } v; v.f = f;
    unsigned r = v.u + 0x7FFFu + ((v.u >> 16) & 1u);
    return (ushort)(r >> 16);
}

__device__ __forceinline__ float fastrcp(float x) {  // v_rcp_f32, ~1e-5 rel err
    return __builtin_amdgcn_rcpf(x);
}

// blocks [0,nT): per-tile bucket histogram -> histg[block][bucket]
// blocks [nT,nT+MBBLK): weight fold  Mb[j][k] = bf16(sum_t W[k][t]*L[t][j])
__global__ __launch_bounds__(512) void hist_build_kernel(
    const int* __restrict__ dsts, int* __restrict__ histg, int E, int B, int nT,
    const float* __restrict__ Wz, const float* __restrict__ bz,
    const float* __restrict__ Wh, const float* __restrict__ bh,
    const float* __restrict__ Lzw, const float* __restrict__ Lzb,
    const float* __restrict__ Lhw, const float* __restrict__ Lhb,
    ushort* __restrict__ Mb, float* __restrict__ cb) {
    __shared__ int h[BMAX];
    if (blockIdx.x < nT) {
        for (int i = threadIdx.x; i < B; i += 512) h[i] = 0;
        __syncthreads();
        int tile0 = blockIdx.x * TILE;
#pragma unroll 4
        for (int j = 0; j < TILE / 512; ++j) {
            int e = tile0 + j * 512 + threadIdx.x;
            if (e < E) atomicAdd(&h[((unsigned)dsts[e]) >> SHIFT], 1);
        }
        __syncthreads();
        for (int i = threadIdx.x; i < B; i += 512)
            histg[blockIdx.x * BMAX + i] = h[i];
    } else {
        int j = (blockIdx.x - nT) * 8 + (threadIdx.x >> 6);   // 0..511
        int k = threadIdx.x & 63;                             // 0..63
        int which = j >> 8;
        int jj = j & 255;
        const float* W  = which ? Wh  : Wz;
        const float* bv = which ? bh  : bz;
        const float* L  = which ? Lhw : Lzw;   // [512,256]; rows 0..255 (H0=0)
        const float* Lb = which ? Lhb : Lzb;
        float acc = 0.f;
        for (int t = 0; t < 256; ++t) acc = fmaf(W[k * 256 + t], L[t * 256 + jj], acc);
        Mb[j * 64 + k] = f2b(acc);
        if (k == 0) {
            float a = 0.f;
            for (int t = 0; t < 256; ++t) a = fmaf(bv[t], L[t * 256 + jj], a);
            cb[j] = a + Lb[jj];
        }
    }
}

// one block per bucket: exclusive scan of histg[.][b] over blocks (in place),
// column total -> bdeg[b]
__global__ __launch_bounds__(512) void colscan_kernel(int* __restrict__ histg,
                                                      int* __restrict__ bdeg,
                                                      int nT) {
    int b = blockIdx.x;
    int tid = threadIdx.x;
    __shared__ int sv[512];
    int v = (tid < nT) ? histg[tid * BMAX + b] : 0;
    sv[tid] = v;
    __syncthreads();
    for (int off = 1; off < 512; off <<= 1) {
        int t = (tid >= off) ? sv[tid - off] : 0;
        __syncthreads();
        sv[tid] += t;
        __syncthreads();
    }
    if (tid < nT) histg[tid * BMAX + b] = sv[tid] - v;   // exclusive
    if (tid == 0) bdeg[b] = sv[511];                      // column total
}

// single block: bbase = exclusive scan of bdeg
__global__ __launch_bounds__(BMAX) void bucket_prefix_kernel(const int* __restrict__ bdeg,
                                                             int* __restrict__ bbase, int B) {
    __shared__ int sv[BMAX];
    int tid = threadIdx.x;
    int v = (tid < B) ? bdeg[tid] : 0;
    sv[tid] = v;
    __syncthreads();
    for (int off = 1; off < BMAX; off <<= 1) {
        int t = (tid >= off) ? sv[tid - off] : 0;
        __syncthreads();
        sv[tid] += t;
        __syncthreads();
    }
    if (tid < B) bbase[tid] = sv[tid] - v;
}

// tile scatter with deterministic run bases (bbase[b] + histg[blk][b]) and
// LDS-only cursors — no global atomics. Packed (dstLocal<<17 | src).
__global__ __launch_bounds__(512) void scatter2_kernel(const int* __restrict__ srcs,
                                                       const int* __restrict__ dsts,
                                                       const int* __restrict__ histg,
                                                       const int* __restrict__ bbase,
                                                       int* __restrict__ staging,
                                                       int E, int B) {
    __shared__ int cur[BMAX];
    int tid = threadIdx.x;
    for (int i = tid; i < B; i += 512)
        cur[i] = bbase[i] + histg[blockIdx.x * BMAX + i];
    __syncthreads();
    int tile0 = blockIdx.x * TILE;
#pragma unroll 4
    for (int j = 0; j < TILE / 512; ++j) {
        int e = tile0 + j * 512 + threadIdx.x;
        if (e < E) {
            int d = dsts[e], s = srcs[e];
            int b = ((unsigned)d) >> SHIFT;
            int pos = atomicAdd(&cur[b], 1);   // LDS atomic only
            staging[pos] = ((d & (NPB - 1)) << 17) | s;
        }
    }
}

// one block per bucket: deg counted from the bucket's staging window via
// LDS histogram atomics, deg written coalesced; then the bucket's xs rows:
// xs[s][c] = fp16(x[s][c]*dinv[s]) (dinv held in LDS only).
__global__ __launch_bounds__(512) void prep_kernel(const int* __restrict__ staging,
                                                   const int* __restrict__ bdeg,
                                                   const int* __restrict__ bbase,
                                                   const float* __restrict__ x,
                                                   int* __restrict__ deg,
                                                   __half* __restrict__ xs,
                                                   int n, int B) {
    int b = blockIdx.x;
    int tid = threadIdx.x;
    __shared__ int nd[NPB];
    __shared__ float sdinv[NPB];
    if (tid < NPB) nd[tid] = 0;
    __syncthreads();
    int count = bdeg[b];
    int base  = bbase[b];
    for (int i = tid; i < count; i += 512)
        atomicAdd(&nd[staging[base + i] >> 17], 1);
    __syncthreads();
    if (tid < NPB) {
        int dg = nd[tid];
        float dn = rsqrtf((float)dg + 1.0f);
        sdinv[tid] = dn;
        int node = (b << SHIFT) + tid;
        if (node < n) deg[node] = dg;
    }
    __syncthreads();
    int nbase = b << SHIFT;
    for (int i2 = tid; i2 < NPB * 16; i2 += 512) {
        int nl = i2 >> 4;
        int node = nbase + nl;
        if (node < n) {
            float dn = sdinv[nl];
            size_t gi = (size_t)node * 16 + (i2 & 15);
            float4 vx = ((const float4*)x)[gi];
            __half2 a = __floats2half2_rn(vx.x * dn, vx.y * dn);
            __half2 c = __floats2half2_rn(vx.z * dn, vx.w * dn);
            ((__half2*)xs)[gi * 2 + 0] = a;
            ((__half2*)xs)[gi * 2 + 1] = c;
        }
    }
}

// One block per 128-node bucket, 512 thr = 8 waves.
// Phase 1: counting sort of the bucket's staging window into LDS csrl.
// Phase 2: register gather (random xs reads); eg==0 lanes deposit agg rows
//   into aggl in MFMA A-fragment order [st][kc][quad][nidx] (wave-private).
// Phase 3: per-wave 32 gate-cols: 64 MFMA + gate transcendentals; head via
//   width-16 shfl reduce + LDS f32 atomics into part[128][4].
// Phase 4: 128-thread softmax epilogue -> out.
__global__ __launch_bounds__(512, 6) void fused_gather_mfma_kernel(
    const int* __restrict__ staging,
    const int* __restrict__ bdeg,
    const int* __restrict__ bbase,
    const int* __restrict__ deg,
    const __half* __restrict__ xs,
    const ushort* __restrict__ Mb,     // [512][64] bf16 (B layout)
    const float* __restrict__ cb,      // [512]
    const float* __restrict__ Wo, const float* __restrict__ bo,
    float* __restrict__ out, int n) {
    int b   = blockIdx.x;
    int tid = threadIdx.x;
    __shared__ int   csrl[CAP];
    __shared__ int   sstart[NPB];
    __shared__ int   ncur[NPB];
    __shared__ int   sdeg[NPB];
    __shared__ int   ssc[NPB];
    __shared__ float sdinv[NPB];
    __shared__ uint4 aggl[NPB * 8];    // 16KB: [st][kc][quad][nidx] 16B units
    __shared__ float part[NPB][4];
    int node0 = b << SHIFT;
    int count = bdeg[b];
    int base  = bbase[b];
    if (tid < NPB) {
        int nodeid = node0 + tid;
        int dg = (nodeid < n) ? deg[nodeid] : 0;
        sdeg[tid] = dg;
        ssc[tid]  = dg;
        sdinv[tid] = rsqrtf((float)dg + 1.0f);
    }
    ((float*)part)[tid] = 0.f;
    __syncthreads();
    for (int off = 1; off < NPB; off <<= 1) {
        int t = 0;
        if (tid < NPB && tid >= off) t = ssc[tid - off];
        __syncthreads();
        if (tid < NPB) ssc[tid] += t;
        __syncthreads();
    }
    if (tid < NPB) {
        int excl = ssc[tid] - sdeg[tid];
        sstart[tid] = excl;
        ncur[tid]   = excl;
    }
    __syncthreads();
    // counting-sort scatter: one coalesced staging pass, LDS stores only
    for (int i = tid; i < count; i += 512) {
        int p = staging[base + i];
        int pos = atomicAdd(&ncur[p >> 17], 1);
        if (pos < CAP) csrl[pos] = p & 0x1FFFF;   // never fires in practice
    }
    __syncthreads();
    int wv = tid >> 6, lane = tid & 63;
    int eg = lane >> 3;      // edge group 0..7
    int c  = lane & 7;       // 16B chunk (8 halfs)
    for (int t16 = 0; t16 < 16; ++t16) {
        int nl   = (wv << 4) + t16;
        int node = node0 + nl;
        int s0 = sstart[nl];
        int d  = sdeg[nl];
        __half2 hz = __float2half2_rn(0.f);
        __half2 hacc[4] = {hz, hz, hz, hz};
        int full = d & ~15;
        for (int be = 0; be < full; be += 16) {
            int qb = s0 + be;
            if (qb > CAP - 16) qb = CAP - 16;    // safety clamp, never binds
            int i0 = csrl[qb + eg];
            int i1 = csrl[qb + 8 + eg];
            union { uint4 u; __half2 h[4]; } p0, p1;
            p0.u = *(const uint4*)(xs + (size_t)i0 * 64 + c * 8);
            p1.u = *(const uint4*)(xs + (size_t)i1 * 64 + c * 8);
#pragma unroll
            for (int t = 0; t < 4; ++t) hacc[t] = __hadd2(hacc[t], p0.h[t]);
#pragma unroll
            for (int t = 0; t < 4; ++t) hacc[t] = __hadd2(hacc[t], p1.h[t]);
        }
        if (full < d) {   // ragged tail (< 16 edges)
            int e0 = full + eg;
            int e1 = full + 8 + eg;
            int q0 = s0 + (e0 < d ? e0 : d - 1);
            int q1 = s0 + (e1 < d ? e1 : d - 1);
            if (q0 > CAP - 1) q0 = CAP - 1;
            if (q1 > CAP - 1) q1 = CAP - 1;
            int i0 = csrl[q0];
            int i1 = csrl[q1];
            union { uint4 u; __half2 h[4]; } p0, p1;
            p0.u = *(const uint4*)(xs + (size_t)i0 * 64 + c * 8);
            p1.u = *(const uint4*)(xs + (size_t)i1 * 64 + c * 8);
            if (e0 >= d) p0.u = make_uint4(0u, 0u, 0u, 0u);
            if (e1 >= d) p1.u = make_uint4(0u, 0u, 0u, 0u);
#pragma unroll
            for (int t = 0; t < 4; ++t) hacc[t] = __hadd2(hacc[t], p0.h[t]);
#pragma unroll
            for (int t = 0; t < 4; ++t) hacc[t] = __hadd2(hacc[t], p1.h[t]);
        }
#pragma unroll
        for (int off = 32; off >= 8; off >>= 1) {
#pragma unroll
            for (int t = 0; t < 4; ++t) {
                union { __half2 h; int i; } u;
                u.h = hacc[t];
                u.i = __shfl_down(u.i, off);
                hacc[t] = __hadd2(hacc[t], u.h);
            }
        }
        if (eg == 0) {
            uint4 o = make_uint4(0u, 0u, 0u, 0u);
            if (node < n) {
                float dn = sdinv[nl];
                union { uint4 u; __half2 h[4]; } p;
                p.u = *(const uint4*)(xs + (size_t)node * 64 + c * 8);
                unsigned* ow = (unsigned*)&o;
#pragma unroll
                for (int t = 0; t < 4; ++t) {
                    float2 a = __half22float2(hacc[t]);
                    float2 f = __half22float2(p.h[t]);
                    float v0 = dn * fmaf(f.x, dn, a.x);
                    float v1 = dn * fmaf(f.y, dn, a.y);
                    ow[t] = (unsigned)f2b(v0) | ((unsigned)f2b(v1) << 16);
                }
            }
            // fragment order: st = nl>>4 (== wv), kc = c>>2, quad = c&3
            aggl[(((nl >> 4) * 2 + (c >> 2)) * 4 + (c & 3)) * 16 + (nl & 15)] = o;
        }
    }
    __syncthreads();
    // ---- MFMA + gates + head ----
    int nidx = lane & 15;
    int quad = lane >> 4;
    int colZ0 = (wv << 5) + nidx;      // wave owns cols colZ0, colZ0+16
    int colZ1 = colZ0 + 16;
    short8 bz0[2], bz1[2], bh0[2], bh1[2];
#pragma unroll
    for (int s = 0; s < 2; ++s) {
        bz0[s] = *(const short8*)(Mb + colZ0 * 64 + s * 32 + quad * 8);
        bz1[s] = *(const short8*)(Mb + colZ1 * 64 + s * 32 + quad * 8);
        bh0[s] = *(const short8*)(Mb + (256 + colZ0) * 64 + s * 32 + quad * 8);
        bh1[s] = *(const short8*)(Mb + (256 + colZ1) * 64 + s * 32 + quad * 8);
    }
    float cbz0 = cb[colZ0], cbz1 = cb[colZ1];
    float cbh0 = cb[256 + colZ0], cbh1 = cb[256 + colZ1];
    float4 wo0 = ((const float4*)Wo)[colZ0];
    float4 wo1 = ((const float4*)Wo)[colZ1];
#pragma unroll
    for (int st = 0; st < NPB / 16; ++st) {   // 8 subtiles of 16 nodes
        short8 a0 = *(const short8*)&aggl[((st * 2 + 0) * 4 + quad) * 16 + nidx];
        short8 a1 = *(const short8*)&aggl[((st * 2 + 1) * 4 + quad) * 16 + nidx];
        // cg 0 (col colZ0)
        {
            floatx4 cz = {cbz0, cbz0, cbz0, cbz0};
            cz = __builtin_amdgcn_mfma_f32_16x16x32_bf16(a0, bz0[0], cz, 0, 0, 0);
            cz = __builtin_amdgcn_mfma_f32_16x16x32_bf16(a1, bz0[1], cz, 0, 0, 0);
            floatx4 ch = {cbh0, cbh0, cbh0, cbh0};
            ch = __builtin_amdgcn_mfma_f32_16x16x32_bf16(a0, bh0[0], ch, 0, 0, 0);
            ch = __builtin_amdgcn_mfma_f32_16x16x32_bf16(a1, bh0[1], ch, 0, 0, 0);
#pragma unroll
            for (int r = 0; r < 4; ++r) {
                float zc = fastrcp(1.0f + __expf(cz[r]));     // 1 - sigmoid
                float th = 1.0f - 2.0f * fastrcp(1.0f + __expf(2.0f * ch[r]));
                float hv = fmaxf(zc * th, 0.0f);
                float s0_ = hv * wo0.x, s1_ = hv * wo0.y;
                float s2_ = hv * wo0.z, s3_ = hv * wo0.w;
#pragma unroll
                for (int off = 8; off > 0; off >>= 1) {
                    s0_ += __shfl_down(s0_, off, 16);
                    s1_ += __shfl_down(s1_, off, 16);
                    s2_ += __shfl_down(s2_, off, 16);
                    s3_ += __shfl_down(s3_, off, 16);
                }
                if (nidx == 0) {
                    int row = (st << 4) + (quad << 2) + r;
                    atomicAdd(&part[row][0], s0_);
                    atomicAdd(&part[row][1], s1_);
                    atomicAdd(&part[row][2], s2_);
                    atomicAdd(&part[row][3], s3_);
                }
            }
        }
        // cg 1 (col colZ1)
        {
            floatx4 cz = {cbz1, cbz1, cbz1, cbz1};
            cz = __builtin_amdgcn_mfma_f32_16x16x32_bf16(a0, bz1[0], cz, 0, 0, 0);
            cz = __builtin_amdgcn_mfma_f32_16x16x32_bf16(a1, bz1[1], cz, 0, 0, 0);
            floatx4 ch = {cbh1, cbh1, cbh1, cbh1};
            ch = __builtin_amdgcn_mfma_f32_16x16x32_bf16(a0, bh1[0], ch, 0, 0, 0);
            ch = __builtin_amdgcn_mfma_f32_16x16x32_bf16(a1, bh1[1], ch, 0, 0, 0);
#pragma unroll
            for (int r = 0; r < 4; ++r) {
                float zc = fastrcp(1.0f + __expf(cz[r]));
                float th = 1.0f - 2.0f * fastrcp(1.0f + __expf(2.0f * ch[r]));
                float hv = fmaxf(zc * th, 0.0f);
                float s0_ = hv * wo1.x, s1_ = hv * wo1.y;
                float s2_ = hv * wo1.z, s3_ = hv * wo1.w;
#pragma unroll
                for (int off = 8; off > 0; off >>= 1) {
                    s0_ += __shfl_down(s0_, off, 16);
                    s1_ += __shfl_down(s1_, off, 16);
                    s2_ += __shfl_down(s2_, off, 16);
                    s3_ += __shfl_down(s3_, off, 16);
                }
                if (nidx == 0) {
                    int row = (st << 4) + (quad << 2) + r;
                    atomicAdd(&part[row][0], s0_);
                    atomicAdd(&part[row][1], s1_);
                    atomicAdd(&part[row][2], s2_);
                    atomicAdd(&part[row][3], s3_);
                }
            }
        }
    }
    __syncthreads();
    if (tid < NPB) {
        int node = node0 + tid;
        if (node < n) {
            float v0 = part[tid][0] + bo[0];
            float v1 = part[tid][1] + bo[1];
            float v2 = part[tid][2] + bo[2];
            float v3 = part[tid][3] + bo[3];
            float mx = fmaxf(fmaxf(v0, v1), fmaxf(v2, v3));
            float e0 = __expf(v0 - mx), e1 = __expf(v1 - mx);
            float e2 = __expf(v2 - mx), e3 = __expf(v3 - mx);
            float inv = fastrcp(e0 + e1 + e2 + e3);
            float4 o;
            o.x = e0 * inv; o.y = e1 * inv; o.z = e2 * inv; o.w = e3 * inv;
            ((float4*)out)[node] = o;
        }
    }
}

extern "C" void kernel_launch(void* const* d_in, const int* in_sizes, int n_in,
                              void* d_out, int out_size, void* d_ws, size_t ws_size,
                              hipStream_t stream) {
    const float* x   = (const float*)d_in[0];
    const int*  eidx = (const int*)d_in[1];
    const float* Wz  = (const float*)d_in[2];
    const float* bz  = (const float*)d_in[3];
    // d_in[4]=Wr, d_in[5]=br : dead (H0 = 0)
    const float* Wh  = (const float*)d_in[6];
    const float* bh  = (const float*)d_in[7];
    const float* Lzw = (const float*)d_in[8];
    const float* Lzb = (const float*)d_in[9];
    // d_in[10]=Lrw, d_in[11]=Lrb : dead
    const float* Lhw = (const float*)d_in[12];
    const float* Lhb = (const float*)d_in[13];
    const float* Wo  = (const float*)d_in[14];
    const float* bo  = (const float*)d_in[15];
    float* out = (float*)d_out;

    int n = in_sizes[0] / 64;
    int E = in_sizes[1] / 2;
    const int* srcs = eidx;
    const int* dsts = eidx + E;
    int B = (n + NPB - 1) >> SHIFT;
    int nT = (E + TILE - 1) / TILE;          // tiles (<= 512 for E <= 4.2M)

    size_t na = ((size_t)n + 3) & ~(size_t)3;
    size_t stageBytes = ((size_t)E * 4 + 255) & ~(size_t)255;

    char* ws = (char*)d_ws;
    int*   deg   = (int*)ws;    ws += na * 4;
    int*   bdeg  = (int*)ws;    ws += BMAX * 4;
    int*   bbase = (int*)ws;    ws += BMAX * 4;
    int*   histg = (int*)ws;    ws += (size_t)nT * BMAX * 4;
    int*   staging = (int*)ws;  ws += stageBytes;       // live through fused
    __half* xs   = (__half*)ws; ws += (size_t)n * 64 * 2;
    ushort* Mb   = (ushort*)ws; ws += 512 * 64 * 2;
    float* cb    = (float*)ws;  ws += 512 * 4;

    hist_build_kernel<<<nT + MBBLK, 512, 0, stream>>>(dsts, histg, E, B, nT,
                                                      Wz, bz, Wh, bh,
                                                      Lzw, Lzb, Lhw, Lhb, Mb, cb);
    colscan_kernel<<<B, 512, 0, stream>>>(histg, bdeg, nT);
    bucket_prefix_kernel<<<1, BMAX, 0, stream>>>(bdeg, bbase, B);
    scatter2_kernel<<<nT, 512, 0, stream>>>(srcs, dsts, histg, bbase, staging,
                                            E, B);
    prep_kernel<<<B, 512, 0, stream>>>(staging, bdeg, bbase, x, deg, xs, n, B);
    fused_gather_mfma_kernel<<<B, 512, 0, stream>>>(staging, bdeg, bbase, deg,
                                                    xs, Mb, cb, Wo, bo, out, n);
}

// Round 6
// 252.128 us; speedup vs baseline: 1.4567x; 1.4567x over previous
//
#include <hip/hip_runtime.h>
#include <hip/hip_fp16.h>

// TGCN forward, algebraically reduced (H0 = 0 => R/Wr dead, Z*H = 0):
//   deg[d] = #in-edges of d ; dinv = rsqrt(deg+1)
//   xs[s]  = fp16( x[s] * dinv[s] )
//   agg[d] = bf16( dinv[d] * ( sum_{e: dst=d} xs[src] + xs[d]*dinv[d] ) )
//   M = [Wz@Lzw_top | Wh@Lhw_top]  (64x512, bf16, MFMA B-layout), cb = bias fold
//   out = softmax(relu((1-Z)*Ht) @ Wo + bo)
//
// R1 -> R2: atomic scatter (2700us) -> CSR build + register gather.
// R3 -> R4: scatter write amp -> 2-level bucket sort (793 -> 455us).
// R7 -> R8: node GEMM -> mfma_f32_16x16x32_bf16 (412 -> off top-5).
// R14 -> R15: epilogue fp32 divides -> v_rcp_f32 (304 -> 275.7).
// R16: 9 -> 6 launches NEUTRAL: graph capture amortizes launches.
// R17: LDS ds_add_f32 per-edge accumulation DISASTER (1339us): LDS atomics
//   only as occasional ops, never the per-element primitive.
// R18: deg via 3.2M scattered global atomics = 130us (device-scope atomics
//   -> memory-side round trip each). Occasional only.
// R19: LDS-resident csr gather + LDS-histogram deg. 264.5us best.
// R20: fuse node_mfma into gather. FAILED (367; fused=191): 44.5KB LDS ->
//   3 blk/CU, random-read BW 2.8->0.9 TB/s; shfl-storm head serialized the
//   LDS pipe; MFMA itself was only ~2.6us. REVERTED. But R20 gave clean
//   attribution: front-end (hist/colscan/prefix/scatter2/prep) ~ 176us,
//   bucket_gather 62, node_mfma ~26.
// R20 -> R21: consolidate front-end. Bucket-strided preallocation
//   (staging[b*CAPB], CAPB=9216=mean+11sigma): one fused kernel does
//   LDS tile-hist -> ~391 block-granular global atomic reserves (200K
//   total, the "occasional" kind) -> LDS-cursor scatter. Deletes hist's
//   extra dsts pass, colscan, prefix, histg traffic, 2 kernel boundaries.
//   prep/bucket_gather/node_mfma = proven R19 code with base=b*CAPB,
//   count=gcur[b]. Within-bucket order now nondeterministic across tiles:
//   fp16 reorder jitter << bf16 quantization floor.

#define SHIFT 8
#define NPB   256          // nodes per bucket (=1<<SHIFT)
#define BMAX  512          // max buckets (n <= 131072 for 17-bit src packing)
#define TILE  8192         // edges per tile (scatter blocks)
#define MBBLK 64           // fused build_m blocks (512 j-cols / 8 per block)
#define CAP   7936         // LDS csr entries per half-bucket (mean 4096, sd 64)
#define CAPB  9216         // staging slots per bucket (mean 8192, sd 90)

typedef __attribute__((ext_vector_type(8))) short short8;
typedef __attribute__((ext_vector_type(4))) float floatx4;

__device__ __forceinline__ ushort f2b(float f) {   // fp32 -> bf16 RNE
    union { float f; unsigned u; } v; v.f = f;
    unsigned r = v.u + 0x7FFFu + ((v.u >> 16) & 1u);
    return (ushort)(r >> 16);
}

__device__ __forceinline__ float fastrcp(float x) {  // v_rcp_f32, ~1e-5 rel err
    return __builtin_amdgcn_rcpf(x);
}

// blocks [0,nT): LDS tile-hist -> block-granular global reserve -> LDS-cursor
//   scatter into the bucket's private region staging[b*CAPB + ...].
// blocks [nT,nT+MBBLK): weight fold  Mb[j][k] = bf16(sum_t W[k][t]*L[t][j])
__global__ __launch_bounds__(512) void scatter_build_kernel(
    const int* __restrict__ srcs, const int* __restrict__ dsts,
    int* __restrict__ gcur, int* __restrict__ staging, int E, int B, int nT,
    const float* __restrict__ Wz, const float* __restrict__ bz,
    const float* __restrict__ Wh, const float* __restrict__ bh,
    const float* __restrict__ Lzw, const float* __restrict__ Lzb,
    const float* __restrict__ Lhw, const float* __restrict__ Lhb,
    ushort* __restrict__ Mb, float* __restrict__ cb) {
    __shared__ int h[BMAX];    // counts, then per-bucket cursor (local offset)
    if (blockIdx.x < nT) {
        int tid = threadIdx.x;
        for (int i = tid; i < B; i += 512) h[i] = 0;
        __syncthreads();
        int tile0 = blockIdx.x * TILE;
#pragma unroll 4
        for (int j = 0; j < TILE / 512; ++j) {
            int e = tile0 + j * 512 + tid;
            if (e < E) atomicAdd(&h[((unsigned)dsts[e]) >> SHIFT], 1);
        }
        __syncthreads();
        for (int i = tid; i < B; i += 512) {
            int c = h[i];
            h[i] = (c > 0) ? atomicAdd(&gcur[i], c) : 0;   // reserve segment
        }
        __syncthreads();
#pragma unroll 4
        for (int j = 0; j < TILE / 512; ++j) {
            int e = tile0 + j * 512 + tid;
            if (e < E) {
                int d = dsts[e], s = srcs[e];          // dsts re-read: L2-hot
                int b = ((unsigned)d) >> SHIFT;
                int pos = atomicAdd(&h[b], 1);         // LDS cursor
                if (pos < CAPB)
                    staging[(size_t)b * CAPB + pos] = ((d & (NPB - 1)) << 17) | s;
            }
        }
    } else {
        int j = (blockIdx.x - nT) * 8 + (threadIdx.x >> 6);   // 0..511
        int k = threadIdx.x & 63;                             // 0..63
        int which = j >> 8;
        int jj = j & 255;
        const float* W  = which ? Wh  : Wz;
        const float* bv = which ? bh  : bz;
        const float* L  = which ? Lhw : Lzw;   // [512,256]; rows 0..255 (H0=0)
        const float* Lb = which ? Lhb : Lzb;
        float acc = 0.f;
        for (int t = 0; t < 256; ++t) acc = fmaf(W[k * 256 + t], L[t * 256 + jj], acc);
        Mb[j * 64 + k] = f2b(acc);
        if (k == 0) {
            float a = 0.f;
            for (int t = 0; t < 256; ++t) a = fmaf(bv[t], L[t * 256 + jj], a);
            cb[j] = a + Lb[jj];
        }
    }
}

// one block per bucket: deg counted from the bucket's staging window via
// LDS histogram atomics, deg written coalesced; then the bucket's xs rows:
// xs[s][c] = fp16(x[s][c]*dinv[s]) (dinv held in LDS only).
__global__ __launch_bounds__(512) void prep_kernel(const int* __restrict__ staging,
                                                   const int* __restrict__ gcur,
                                                   const float* __restrict__ x,
                                                   int* __restrict__ deg,
                                                   __half* __restrict__ xs,
                                                   int n, int B) {
    int b = blockIdx.x;
    int tid = threadIdx.x;
    __shared__ int nd[NPB];
    __shared__ float sdinv[NPB];
    if (tid < NPB) nd[tid] = 0;
    __syncthreads();
    int count = gcur[b];
    if (count > CAPB) count = CAPB;
    size_t base = (size_t)b * CAPB;
    for (int i = tid; i < count; i += 512)
        atomicAdd(&nd[staging[base + i] >> 17], 1);
    __syncthreads();
    if (tid < NPB) {
        int dg = nd[tid];
        float dn = rsqrtf((float)dg + 1.0f);
        sdinv[tid] = dn;
        int node = (b << SHIFT) + tid;
        if (node < n) deg[node] = dg;
    }
    __syncthreads();
    int nbase = b << SHIFT;
    for (int i2 = tid; i2 < NPB * 16; i2 += 512) {
        int nl = i2 >> 4;
        int node = nbase + nl;
        if (node < n) {
            float dn = sdinv[nl];
            size_t gi = (size_t)node * 16 + (i2 & 15);
            float4 vx = ((const float4*)x)[gi];
            __half2 a = __floats2half2_rn(vx.x * dn, vx.y * dn);
            __half2 c = __floats2half2_rn(vx.z * dn, vx.w * dn);
            ((__half2*)xs)[gi * 2 + 0] = a;
            ((__half2*)xs)[gi * 2 + 1] = c;
        }
    }
}

// 2 blocks per bucket (node-halves of 128). Counting sort INTO LDS:
// deg row -> scan -> cursor scatter of the bucket's staging window into
// csrl[CAP] (scattered stores hit LDS, not HBM). Then the register gather:
// wave w owns 16 nodes; lane = (edge_group 0..7) x (16B chunk 0..7); edge
// indices read via conflict-free LDS broadcast. fp16 accumulate, bf16 out.
__global__ __launch_bounds__(512) void bucket_gather_kernel(
    const int* __restrict__ staging,
    const int* __restrict__ gcur,
    const int* __restrict__ deg,
    const __half* __restrict__ xs,
    ushort* __restrict__ aggb, int n, int B) {
    int b    = blockIdx.x >> 1;
    int half = blockIdx.x & 1;
    int tid  = threadIdx.x;
    __shared__ int   csrl[CAP];
    __shared__ int   sstart[128];
    __shared__ int   ncur[128];
    __shared__ int   sdeg[128];
    __shared__ int   ssc[128];
    __shared__ float sdinv[128];
    int node0 = (b << SHIFT) + (half << 7);
    int count = gcur[b];
    if (count > CAPB) count = CAPB;
    size_t base = (size_t)b * CAPB;
    if (tid < 128) {
        int nodeid = node0 + tid;
        int dg = (nodeid < n) ? deg[nodeid] : 0;
        sdeg[tid] = dg;
        ssc[tid]  = dg;
        sdinv[tid] = rsqrtf((float)dg + 1.0f);
    }
    __syncthreads();
    for (int off = 1; off < 128; off <<= 1) {
        int t = 0;
        if (tid < 128 && tid >= off) t = ssc[tid - off];
        __syncthreads();
        if (tid < 128) ssc[tid] += t;
        __syncthreads();
    }
    if (tid < 128) {
        int excl = ssc[tid] - sdeg[tid];
        sstart[tid] = excl;
        ncur[tid]   = excl;
    }
    __syncthreads();
    // counting-sort scatter: one coalesced staging pass, LDS stores only
    for (int i = tid; i < count; i += 512) {
        int p  = staging[base + i];
        int dl = p >> 17;
        if ((dl >> 7) == half) {
            int pos = atomicAdd(&ncur[dl & 127], 1);
            if (pos < CAP) csrl[pos] = p & 0x1FFFF;   // never fires in practice
        }
    }
    __syncthreads();
    // register gather (identical numerics to the R16 gather kernel)
    int wv = tid >> 6, lane = tid & 63;
    int eg = lane >> 3;      // edge group 0..7
    int c  = lane & 7;       // 16B chunk (8 halfs)
    for (int t16 = 0; t16 < 16; ++t16) {
        int nl   = (wv << 4) + t16;
        int node = node0 + nl;
        int s0 = sstart[nl];
        int d  = sdeg[nl];
        __half2 hz = __float2half2_rn(0.f);
        __half2 hacc[4] = {hz, hz, hz, hz};
        int full = d & ~15;
        for (int be = 0; be < full; be += 16) {
            int qb = s0 + be;
            if (qb > CAP - 16) qb = CAP - 16;    // safety clamp, never binds
            int i0 = csrl[qb + eg];
            int i1 = csrl[qb + 8 + eg];
            union { uint4 u; __half2 h[4]; } p0, p1;
            p0.u = *(const uint4*)(xs + (size_t)i0 * 64 + c * 8);
            p1.u = *(const uint4*)(xs + (size_t)i1 * 64 + c * 8);
#pragma unroll
            for (int t = 0; t < 4; ++t) hacc[t] = __hadd2(hacc[t], p0.h[t]);
#pragma unroll
            for (int t = 0; t < 4; ++t) hacc[t] = __hadd2(hacc[t], p1.h[t]);
        }
        if (full < d) {   // ragged tail (< 16 edges)
            int e0 = full + eg;
            int e1 = full + 8 + eg;
            int q0 = s0 + (e0 < d ? e0 : d - 1);
            int q1 = s0 + (e1 < d ? e1 : d - 1);
            if (q0 > CAP - 1) q0 = CAP - 1;
            if (q1 > CAP - 1) q1 = CAP - 1;
            int i0 = csrl[q0];
            int i1 = csrl[q1];
            union { uint4 u; __half2 h[4]; } p0, p1;
            p0.u = *(const uint4*)(xs + (size_t)i0 * 64 + c * 8);
            p1.u = *(const uint4*)(xs + (size_t)i1 * 64 + c * 8);
            if (e0 >= d) p0.u = make_uint4(0u, 0u, 0u, 0u);
            if (e1 >= d) p1.u = make_uint4(0u, 0u, 0u, 0u);
#pragma unroll
            for (int t = 0; t < 4; ++t) hacc[t] = __hadd2(hacc[t], p0.h[t]);
#pragma unroll
            for (int t = 0; t < 4; ++t) hacc[t] = __hadd2(hacc[t], p1.h[t]);
        }
        // packed cross-lane reduce of the 8 edge groups down to eg==0
#pragma unroll
        for (int off = 32; off >= 8; off >>= 1) {
#pragma unroll
            for (int t = 0; t < 4; ++t) {
                union { __half2 h; int i; } u;
                u.h = hacc[t];
                u.i = __shfl_down(u.i, off);
                hacc[t] = __hadd2(hacc[t], u.h);
            }
        }
        if (eg == 0 && node < n) {
            float dn = sdinv[nl];
            union { uint4 u; __half2 h[4]; } p;
            p.u = *(const uint4*)(xs + (size_t)node * 64 + c * 8);
            uint4 o;
            unsigned* ow = (unsigned*)&o;
#pragma unroll
            for (int t = 0; t < 4; ++t) {
                float2 a = __half22float2(hacc[t]);
                float2 f = __half22float2(p.h[t]);
                float v0 = dn * fmaf(f.x, dn, a.x);
                float v1 = dn * fmaf(f.y, dn, a.y);
                ow[t] = (unsigned)f2b(v0) | ((unsigned)f2b(v1) << 16);
            }
            ((uint4*)(aggb + (size_t)node * 64))[c] = o;
        }
    }
}

// 512 threads = 8 waves. Wave w owns cols w*32..w*32+31 for BOTH gates
// (z and ht meet in-register, h=relu((1-z)*ht) -> one h-plane in LDS).
__global__ __launch_bounds__(512) void node_mfma_kernel(
    const ushort* __restrict__ aggb,   // [n][64] bf16
    const ushort* __restrict__ Mb,     // [512][64] bf16 (B layout)
    const float* __restrict__ cb,      // [512]
    const float* __restrict__ Wo, const float* __restrict__ bo,
    float* __restrict__ out, int n) {
    int tid  = threadIdx.x;
    int w    = tid >> 6;
    int lane = tid & 63;
    int nidx = lane & 15;
    int quad = lane >> 4;
    short8 bfz[2][2], bfh[2][2];
    float cbz[2], cbh[2];
#pragma unroll
    for (int cg = 0; cg < 2; ++cg) {
        int colZ = (w << 5) + (cg << 4) + nidx;
        int colH = 256 + colZ;
#pragma unroll
        for (int s = 0; s < 2; ++s) {
            bfz[cg][s] = *(const short8*)(Mb + colZ * 64 + s * 32 + quad * 8);
            bfh[cg][s] = *(const short8*)(Mb + colH * 64 + s * 32 + quad * 8);
        }
        cbz[cg] = cb[colZ];
        cbh[cg] = cb[colH];
    }
    __shared__ float sH[32][260];    // 33 KB h-plane (260 pad: 2-way on stores)
    __shared__ float sWo[4][256];
    if (tid < 256) {
#pragma unroll
        for (int o = 0; o < 4; ++o) sWo[o][tid] = Wo[tid * 4 + o];
    }
    float bo0 = bo[0], bo1 = bo[1], bo2 = bo[2], bo3 = bo[3];
    int ntiles = (n + 31) >> 5;
    for (int tile = blockIdx.x; tile < ntiles; tile += gridDim.x) {
        int node0 = tile << 5;
        int nA0 = node0 + nidx;
        int nA1 = node0 + 16 + nidx;
        if (nA0 >= n) nA0 = n - 1;   // clamp; stores are guarded
        if (nA1 >= n) nA1 = n - 1;
        const ushort* ar0 = aggb + (size_t)nA0 * 64;
        const ushort* ar1 = aggb + (size_t)nA1 * 64;
        short8 a00 = *(const short8*)(ar0 + quad * 8);
        short8 a01 = *(const short8*)(ar0 + 32 + quad * 8);
        short8 a10 = *(const short8*)(ar1 + quad * 8);
        short8 a11 = *(const short8*)(ar1 + 32 + quad * 8);
#pragma unroll
        for (int cg = 0; cg < 2; ++cg) {
            int col = (w << 5) + (cg << 4) + nidx;
#pragma unroll
            for (int grp = 0; grp < 2; ++grp) {
                short8 a0 = grp ? a10 : a00;
                short8 a1 = grp ? a11 : a01;
                floatx4 cz = {cbz[cg], cbz[cg], cbz[cg], cbz[cg]};
                cz = __builtin_amdgcn_mfma_f32_16x16x32_bf16(a0, bfz[cg][0], cz, 0, 0, 0);
                cz = __builtin_amdgcn_mfma_f32_16x16x32_bf16(a1, bfz[cg][1], cz, 0, 0, 0);
                floatx4 chh = {cbh[cg], cbh[cg], cbh[cg], cbh[cg]};
                chh = __builtin_amdgcn_mfma_f32_16x16x32_bf16(a0, bfh[cg][0], chh, 0, 0, 0);
                chh = __builtin_amdgcn_mfma_f32_16x16x32_bf16(a1, bfh[cg][1], chh, 0, 0, 0);
#pragma unroll
                for (int r = 0; r < 4; ++r) {
                    int row = (grp << 4) + (quad << 2) + r;   // node within tile
                    float zc = fastrcp(1.0f + __expf(cz[r]));     // 1 - sigmoid
                    float th = 1.0f - 2.0f * fastrcp(1.0f + __expf(2.0f * chh[r]));
                    sH[row][col] = fmaxf(zc * th, 0.0f);
                }
            }
        }
        __syncthreads();
        {   // head: 16 threads per node, 16 channels each
            int nb = tid >> 4, g = tid & 15;
            float l0 = 0.f, l1 = 0.f, l2 = 0.f, l3 = 0.f;
#pragma unroll
            for (int ii = 0; ii < 16; ++ii) {
                int ch = g + 16 * ii;
                float hv = sH[nb][ch];
                l0 = fmaf(hv, sWo[0][ch], l0);
                l1 = fmaf(hv, sWo[1][ch], l1);
                l2 = fmaf(hv, sWo[2][ch], l2);
                l3 = fmaf(hv, sWo[3][ch], l3);
            }
#pragma unroll
            for (int off = 8; off > 0; off >>= 1) {
                l0 += __shfl_down(l0, off, 16);
                l1 += __shfl_down(l1, off, 16);
                l2 += __shfl_down(l2, off, 16);
                l3 += __shfl_down(l3, off, 16);
            }
            int node = node0 + nb;
            if (g == 0 && node < n) {
                float v0 = l0 + bo0, v1 = l1 + bo1, v2 = l2 + bo2, v3 = l3 + bo3;
                float mx = fmaxf(fmaxf(v0, v1), fmaxf(v2, v3));
                float e0 = __expf(v0 - mx), e1 = __expf(v1 - mx);
                float e2 = __expf(v2 - mx), e3 = __expf(v3 - mx);
                float inv = fastrcp(e0 + e1 + e2 + e3);
                float4 o;
                o.x = e0 * inv; o.y = e1 * inv; o.z = e2 * inv; o.w = e3 * inv;
                ((float4*)out)[node] = o;
            }
        }
        __syncthreads();
    }
}

extern "C" void kernel_launch(void* const* d_in, const int* in_sizes, int n_in,
                              void* d_out, int out_size, void* d_ws, size_t ws_size,
                              hipStream_t stream) {
    const float* x   = (const float*)d_in[0];
    const int*  eidx = (const int*)d_in[1];
    const float* Wz  = (const float*)d_in[2];
    const float* bz  = (const float*)d_in[3];
    // d_in[4]=Wr, d_in[5]=br : dead (H0 = 0)
    const float* Wh  = (const float*)d_in[6];
    const float* bh  = (const float*)d_in[7];
    const float* Lzw = (const float*)d_in[8];
    const float* Lzb = (const float*)d_in[9];
    // d_in[10]=Lrw, d_in[11]=Lrb : dead
    const float* Lhw = (const float*)d_in[12];
    const float* Lhb = (const float*)d_in[13];
    const float* Wo  = (const float*)d_in[14];
    const float* bo  = (const float*)d_in[15];
    float* out = (float*)d_out;

    int n = in_sizes[0] / 64;
    int E = in_sizes[1] / 2;
    const int* srcs = eidx;
    const int* dsts = eidx + E;
    int B = (n + NPB - 1) >> SHIFT;
    int nT = (E + TILE - 1) / TILE;

    size_t na = ((size_t)n + 3) & ~(size_t)3;
    size_t stageBytes = (((size_t)B * CAPB * 4) + 255) & ~(size_t)255;
    size_t aggBytes   = (((size_t)n * 64 * 2) + 255) & ~(size_t)255;

    char* ws = (char*)d_ws;
    int*   deg   = (int*)ws;    ws += na * 4;
    int*   gcur  = (int*)ws;    ws += BMAX * 4;
    int*   staging = (int*)ws;  ws += stageBytes;       // live through gather
    __half* xs   = (__half*)ws; ws += (size_t)n * 64 * 2;
    ushort* aggb = (ushort*)ws; ws += aggBytes;
    ushort* Mb   = (ushort*)ws; ws += 512 * 64 * 2;
    float* cb    = (float*)ws;  ws += 512 * 4;

    hipMemsetAsync(gcur, 0, BMAX * 4, stream);
    scatter_build_kernel<<<nT + MBBLK, 512, 0, stream>>>(srcs, dsts, gcur,
                                                         staging, E, B, nT,
                                                         Wz, bz, Wh, bh,
                                                         Lzw, Lzb, Lhw, Lhb,
                                                         Mb, cb);
    prep_kernel<<<B, 512, 0, stream>>>(staging, gcur, x, deg, xs, n, B);
    bucket_gather_kernel<<<2 * B, 512, 0, stream>>>(staging, gcur, deg,
                                                    xs, aggb, n, B);
    node_mfma_kernel<<<1024, 512, 0, stream>>>(aggb, Mb, cb, Wo, bo, out, n);
}

// Round 7
// 249.481 us; speedup vs baseline: 1.4721x; 1.0106x over previous
//
#include <hip/hip_runtime.h>
#include <hip/hip_fp16.h>

// TGCN forward, algebraically reduced (H0 = 0 => R/Wr dead, Z*H = 0):
//   deg[d] = #in-edges of d ; dinv = rsqrt(deg+1)
//   xs[s]  = fp16( x[s] * dinv[s] )
//   agg[d] = bf16( dinv[d] * ( sum_{e: dst=d} xs[src] + xs[d]*dinv[d] ) )
//   M = [Wz@Lzw_top | Wh@Lhw_top]  (64x512, bf16, MFMA B-layout), cb = bias fold
//   out = softmax(relu((1-Z)*Ht) @ Wo + bo)
//
// R1 -> R2: atomic scatter (2700us) -> CSR build + register gather.
// R3 -> R4: scatter write amp -> 2-level bucket sort (793 -> 455us).
// R7 -> R8: node GEMM -> mfma_f32_16x16x32_bf16 (412 -> off top-5).
// R14 -> R15: epilogue fp32 divides -> v_rcp_f32 (304 -> 275.7).
// R16: 9 -> 6 launches NEUTRAL: graph capture amortizes launches.
// R17: LDS ds_add_f32 per-edge accumulation DISASTER (1339us). Lesson:
//   LDS atomics only as occasional ops, never the per-element primitive.
// R18: deg via 3.2M scattered global atomics = 130us. Lesson: device-scope
//   scattered atomics are memory-side round trips; occasional only.
// R19: LDS-resident csr gather + LDS-histogram deg. 264.5us.
// R20: mega-fusion of node_mfma into gather FAILED (367): LDS-occupancy
//   crush + shfl/LDS-pipe head serialization. Reverted; gave attribution.
// R21: bucket-strided preallocation front-end (LDS tile-hist -> block-
//   granular reserve -> direct scatter). 252.1us best. scatter_build=59.6:
//   WRITE 49.8MB for 12.8MB payload (4x line fragmentation: 64 stores/wave
//   to 64 different bucket regions).
// R21 -> R22: line-friendly staging. scatter_build v2: dsts kept in 16
//   VGPRs (single read), LDS hist -> reserve (unchanged), counting-sort
//   the tile INTO LDS (scattered stores hit LDS — R19 pattern), then
//   wave-per-bucket coalesced run copies to staging. SHIFT 8->7: one
//   gather block per 128-node bucket (window read once, no half discard;
//   csrl 20.5KB so LDS stops limiting occupancy).

#define SHIFT 7
#define NPB   128          // nodes per bucket (=1<<SHIFT)
#define BMAX  1024         // max buckets (n <= 131072 for 17-bit src packing)
#define TILE  8192         // edges per tile (scatter blocks)
#define EPT   16           // edges per thread in a tile (TILE/512)
#define MBBLK 64           // fused build_m blocks (512 j-cols / 8 per block)
#define CAPB  5120         // staging slots per bucket (mean 4096, sd 64)

typedef __attribute__((ext_vector_type(8))) short short8;
typedef __attribute__((ext_vector_type(4))) float floatx4;

__device__ __forceinline__ ushort f2b(float f) {   // fp32 -> bf16 RNE
    union { float f; unsigned u; } v; v.f = f;
    unsigned r = v.u + 0x7FFFu + ((v.u >> 16) & 1u);
    return (ushort)(r >> 16);
}

__device__ __forceinline__ float fastrcp(float x) {  // v_rcp_f32, ~1e-5 rel err
    return __builtin_amdgcn_rcpf(x);
}

// blocks [0,nT): per-tile: dsts -> regs + LDS hist; 1024-wide block scan;
//   block-granular global reserve; counting-sort tile into LDS `sorted`;
//   wave-per-bucket coalesced run copy into staging[b*CAPB + gbase + .].
// blocks [nT,nT+MBBLK): weight fold  Mb[j][k] = bf16(sum_t W[k][t]*L[t][j])
__global__ __launch_bounds__(512) void scatter_build_kernel(
    const int* __restrict__ srcs, const int* __restrict__ dsts,
    int* __restrict__ gcur, int* __restrict__ staging, int E, int B, int nT,
    const float* __restrict__ Wz, const float* __restrict__ bz,
    const float* __restrict__ Wh, const float* __restrict__ bh,
    const float* __restrict__ Lzw, const float* __restrict__ Lzb,
    const float* __restrict__ Lhw, const float* __restrict__ Lhb,
    ushort* __restrict__ Mb, float* __restrict__ cb) {
    __shared__ int cnt[BMAX];     // per-bucket tile count
    __shared__ int ssum[BMAX];    // inclusive scan of cnt
    __shared__ int gbase[BMAX];   // global reserved base
    __shared__ int cur[BMAX];     // LDS scatter cursor (local offset)
    __shared__ int sorted[TILE];  // tile payloads sorted by bucket (32KB)
    if (blockIdx.x < nT) {
        int tid = threadIdx.x;
        for (int i = tid; i < BMAX; i += 512) cnt[i] = 0;
        __syncthreads();
        int tile0 = blockIdx.x * TILE;
        int dreg[EPT];
#pragma unroll
        for (int j = 0; j < EPT; ++j) {
            int e = tile0 + j * 512 + tid;
            dreg[j] = (e < E) ? dsts[e] : -1;
            if (dreg[j] >= 0) atomicAdd(&cnt[((unsigned)dreg[j]) >> SHIFT], 1);
        }
        __syncthreads();
        // inclusive 1024-wide Hillis-Steele scan (2 elems/thread)
        {
            int i0 = tid, i1 = tid + 512;
            ssum[i0] = cnt[i0];
            ssum[i1] = cnt[i1];
            __syncthreads();
            for (int off = 1; off < BMAX; off <<= 1) {
                int t0 = (i0 >= off) ? ssum[i0 - off] : 0;
                int t1 = (i1 >= off) ? ssum[i1 - off] : 0;
                __syncthreads();
                ssum[i0] += t0;
                ssum[i1] += t1;
                __syncthreads();
            }
        }
        for (int i = tid; i < BMAX; i += 512) {
            int c = cnt[i];
            gbase[i] = (c > 0) ? atomicAdd(&gcur[i], c) : 0;   // reserve
            cur[i] = ssum[i] - c;                              // local base
        }
        __syncthreads();
        // counting-sort the tile into LDS (scattered stores -> LDS only)
#pragma unroll
        for (int j = 0; j < EPT; ++j) {
            int d = dreg[j];
            if (d >= 0) {
                int e = tile0 + j * 512 + tid;
                int s = srcs[e];
                int b = ((unsigned)d) >> SHIFT;
                int pos = atomicAdd(&cur[b], 1);
                sorted[pos] = ((d & (NPB - 1)) << 17) | s;
            }
        }
        __syncthreads();
        // wave-per-bucket coalesced run copy to global staging
        int wv = tid >> 6, lane = tid & 63;
        for (int b = wv; b < B; b += 8) {
            int c = cnt[b];
            if (c == 0) continue;
            int lb = ssum[b] - c;
            int gb = gbase[b];
            size_t gp = (size_t)b * CAPB + gb;
            for (int j = lane; j < c; j += 64)
                if (gb + j < CAPB) staging[gp + j] = sorted[lb + j];
        }
    } else {
        int j = (blockIdx.x - nT) * 8 + (threadIdx.x >> 6);   // 0..511
        int k = threadIdx.x & 63;                             // 0..63
        int which = j >> 8;
        int jj = j & 255;
        const float* W  = which ? Wh  : Wz;
        const float* bv = which ? bh  : bz;
        const float* L  = which ? Lhw : Lzw;   // [512,256]; rows 0..255 (H0=0)
        const float* Lb = which ? Lhb : Lzb;
        float acc = 0.f;
        for (int t = 0; t < 256; ++t) acc = fmaf(W[k * 256 + t], L[t * 256 + jj], acc);
        Mb[j * 64 + k] = f2b(acc);
        if (k == 0) {
            float a = 0.f;
            for (int t = 0; t < 256; ++t) a = fmaf(bv[t], L[t * 256 + jj], a);
            cb[j] = a + Lb[jj];
        }
    }
}

// one block per 128-node bucket: deg counted from the bucket's staging
// window via LDS histogram atomics, deg written coalesced; then the
// bucket's xs rows: xs[s][c] = fp16(x[s][c]*dinv[s]) (dinv in LDS only).
__global__ __launch_bounds__(512) void prep_kernel(const int* __restrict__ staging,
                                                   const int* __restrict__ gcur,
                                                   const float* __restrict__ x,
                                                   int* __restrict__ deg,
                                                   __half* __restrict__ xs,
                                                   int n, int B) {
    int b = blockIdx.x;
    int tid = threadIdx.x;
    __shared__ int nd[NPB];
    __shared__ float sdinv[NPB];
    if (tid < NPB) nd[tid] = 0;
    __syncthreads();
    int count = gcur[b];
    if (count > CAPB) count = CAPB;
    size_t base = (size_t)b * CAPB;
    for (int i = tid; i < count; i += 512)
        atomicAdd(&nd[staging[base + i] >> 17], 1);
    __syncthreads();
    if (tid < NPB) {
        int dg = nd[tid];
        float dn = rsqrtf((float)dg + 1.0f);
        sdinv[tid] = dn;
        int node = (b << SHIFT) + tid;
        if (node < n) deg[node] = dg;
    }
    __syncthreads();
    int nbase = b << SHIFT;
    for (int i2 = tid; i2 < NPB * 16; i2 += 512) {
        int nl = i2 >> 4;
        int node = nbase + nl;
        if (node < n) {
            float dn = sdinv[nl];
            size_t gi = (size_t)node * 16 + (i2 & 15);
            float4 vx = ((const float4*)x)[gi];
            __half2 a = __floats2half2_rn(vx.x * dn, vx.y * dn);
            __half2 c = __floats2half2_rn(vx.z * dn, vx.w * dn);
            ((__half2*)xs)[gi * 2 + 0] = a;
            ((__half2*)xs)[gi * 2 + 1] = c;
        }
    }
}

// one block per 128-node bucket. Counting sort INTO LDS (window read once):
// deg row -> scan -> cursor scatter into csrl[CAPB]. Then register gather:
// wave w owns 16 nodes; lane = (edge_group 0..7) x (16B chunk 0..7); edge
// indices read via conflict-free LDS broadcast. fp16 accumulate, bf16 out.
__global__ __launch_bounds__(512) void bucket_gather_kernel(
    const int* __restrict__ staging,
    const int* __restrict__ gcur,
    const int* __restrict__ deg,
    const __half* __restrict__ xs,
    ushort* __restrict__ aggb, int n, int B) {
    int b   = blockIdx.x;
    int tid = threadIdx.x;
    __shared__ int   csrl[CAPB];
    __shared__ int   sstart[NPB];
    __shared__ int   ncur[NPB];
    __shared__ int   sdeg[NPB];
    __shared__ int   ssc[NPB];
    __shared__ float sdinv[NPB];
    int node0 = b << SHIFT;
    int count = gcur[b];
    if (count > CAPB) count = CAPB;
    size_t base = (size_t)b * CAPB;
    if (tid < NPB) {
        int nodeid = node0 + tid;
        int dg = (nodeid < n) ? deg[nodeid] : 0;
        sdeg[tid] = dg;
        ssc[tid]  = dg;
        sdinv[tid] = rsqrtf((float)dg + 1.0f);
    }
    __syncthreads();
    for (int off = 1; off < NPB; off <<= 1) {
        int t = 0;
        if (tid < NPB && tid >= off) t = ssc[tid - off];
        __syncthreads();
        if (tid < NPB) ssc[tid] += t;
        __syncthreads();
    }
    if (tid < NPB) {
        int excl = ssc[tid] - sdeg[tid];
        sstart[tid] = excl;
        ncur[tid]   = excl;
    }
    __syncthreads();
    // counting-sort scatter: one coalesced staging pass, LDS stores only
    for (int i = tid; i < count; i += 512) {
        int p = staging[base + i];
        int pos = atomicAdd(&ncur[p >> 17], 1);
        if (pos < CAPB) csrl[pos] = p & 0x1FFFF;
    }
    __syncthreads();
    // register gather (identical numerics to the R16 gather kernel)
    int wv = tid >> 6, lane = tid & 63;
    int eg = lane >> 3;      // edge group 0..7
    int c  = lane & 7;       // 16B chunk (8 halfs)
    for (int t16 = 0; t16 < 16; ++t16) {
        int nl   = (wv << 4) + t16;
        int node = node0 + nl;
        int s0 = sstart[nl];
        int d  = sdeg[nl];
        __half2 hz = __float2half2_rn(0.f);
        __half2 hacc[4] = {hz, hz, hz, hz};
        int full = d & ~15;
        for (int be = 0; be < full; be += 16) {
            int qb = s0 + be;
            if (qb > CAPB - 16) qb = CAPB - 16;    // safety clamp, never binds
            int i0 = csrl[qb + eg];
            int i1 = csrl[qb + 8 + eg];
            union { uint4 u; __half2 h[4]; } p0, p1;
            p0.u = *(const uint4*)(xs + (size_t)i0 * 64 + c * 8);
            p1.u = *(const uint4*)(xs + (size_t)i1 * 64 + c * 8);
#pragma unroll
            for (int t = 0; t < 4; ++t) hacc[t] = __hadd2(hacc[t], p0.h[t]);
#pragma unroll
            for (int t = 0; t < 4; ++t) hacc[t] = __hadd2(hacc[t], p1.h[t]);
        }
        if (full < d) {   // ragged tail (< 16 edges)
            int e0 = full + eg;
            int e1 = full + 8 + eg;
            int q0 = s0 + (e0 < d ? e0 : d - 1);
            int q1 = s0 + (e1 < d ? e1 : d - 1);
            if (q0 > CAPB - 1) q0 = CAPB - 1;
            if (q1 > CAPB - 1) q1 = CAPB - 1;
            int i0 = csrl[q0];
            int i1 = csrl[q1];
            union { uint4 u; __half2 h[4]; } p0, p1;
            p0.u = *(const uint4*)(xs + (size_t)i0 * 64 + c * 8);
            p1.u = *(const uint4*)(xs + (size_t)i1 * 64 + c * 8);
            if (e0 >= d) p0.u = make_uint4(0u, 0u, 0u, 0u);
            if (e1 >= d) p1.u = make_uint4(0u, 0u, 0u, 0u);
#pragma unroll
            for (int t = 0; t < 4; ++t) hacc[t] = __hadd2(hacc[t], p0.h[t]);
#pragma unroll
            for (int t = 0; t < 4; ++t) hacc[t] = __hadd2(hacc[t], p1.h[t]);
        }
        // packed cross-lane reduce of the 8 edge groups down to eg==0
#pragma unroll
        for (int off = 32; off >= 8; off >>= 1) {
#pragma unroll
            for (int t = 0; t < 4; ++t) {
                union { __half2 h; int i; } u;
                u.h = hacc[t];
                u.i = __shfl_down(u.i, off);
                hacc[t] = __hadd2(hacc[t], u.h);
            }
        }
        if (eg == 0 && node < n) {
            float dn = sdinv[nl];
            union { uint4 u; __half2 h[4]; } p;
            p.u = *(const uint4*)(xs + (size_t)node * 64 + c * 8);
            uint4 o;
            unsigned* ow = (unsigned*)&o;
#pragma unroll
            for (int t = 0; t < 4; ++t) {
                float2 a = __half22float2(hacc[t]);
                float2 f = __half22float2(p.h[t]);
                float v0 = dn * fmaf(f.x, dn, a.x);
                float v1 = dn * fmaf(f.y, dn, a.y);
                ow[t] = (unsigned)f2b(v0) | ((unsigned)f2b(v1) << 16);
            }
            ((uint4*)(aggb + (size_t)node * 64))[c] = o;
        }
    }
}

// 512 threads = 8 waves. Wave w owns cols w*32..w*32+31 for BOTH gates
// (z and ht meet in-register, h=relu((1-z)*ht) -> one h-plane in LDS).
__global__ __launch_bounds__(512) void node_mfma_kernel(
    const ushort* __restrict__ aggb,   // [n][64] bf16
    const ushort* __restrict__ Mb,     // [512][64] bf16 (B layout)
    const float* __restrict__ cb,      // [512]
    const float* __restrict__ Wo, const float* __restrict__ bo,
    float* __restrict__ out, int n) {
    int tid  = threadIdx.x;
    int w    = tid >> 6;
    int lane = tid & 63;
    int nidx = lane & 15;
    int quad = lane >> 4;
    short8 bfz[2][2], bfh[2][2];
    float cbz[2], cbh[2];
#pragma unroll
    for (int cg = 0; cg < 2; ++cg) {
        int colZ = (w << 5) + (cg << 4) + nidx;
        int colH = 256 + colZ;
#pragma unroll
        for (int s = 0; s < 2; ++s) {
            bfz[cg][s] = *(const short8*)(Mb + colZ * 64 + s * 32 + quad * 8);
            bfh[cg][s] = *(const short8*)(Mb + colH * 64 + s * 32 + quad * 8);
        }
        cbz[cg] = cb[colZ];
        cbh[cg] = cb[colH];
    }
    __shared__ float sH[32][260];    // 33 KB h-plane (260 pad: 2-way on stores)
    __shared__ float sWo[4][256];
    if (tid < 256) {
#pragma unroll
        for (int o = 0; o < 4; ++o) sWo[o][tid] = Wo[tid * 4 + o];
    }
    float bo0 = bo[0], bo1 = bo[1], bo2 = bo[2], bo3 = bo[3];
    int ntiles = (n + 31) >> 5;
    for (int tile = blockIdx.x; tile < ntiles; tile += gridDim.x) {
        int node0 = tile << 5;
        int nA0 = node0 + nidx;
        int nA1 = node0 + 16 + nidx;
        if (nA0 >= n) nA0 = n - 1;   // clamp; stores are guarded
        if (nA1 >= n) nA1 = n - 1;
        const ushort* ar0 = aggb + (size_t)nA0 * 64;
        const ushort* ar1 = aggb + (size_t)nA1 * 64;
        short8 a00 = *(const short8*)(ar0 + quad * 8);
        short8 a01 = *(const short8*)(ar0 + 32 + quad * 8);
        short8 a10 = *(const short8*)(ar1 + quad * 8);
        short8 a11 = *(const short8*)(ar1 + 32 + quad * 8);
#pragma unroll
        for (int cg = 0; cg < 2; ++cg) {
            int col = (w << 5) + (cg << 4) + nidx;
#pragma unroll
            for (int grp = 0; grp < 2; ++grp) {
                short8 a0 = grp ? a10 : a00;
                short8 a1 = grp ? a11 : a01;
                floatx4 cz = {cbz[cg], cbz[cg], cbz[cg], cbz[cg]};
                cz = __builtin_amdgcn_mfma_f32_16x16x32_bf16(a0, bfz[cg][0], cz, 0, 0, 0);
                cz = __builtin_amdgcn_mfma_f32_16x16x32_bf16(a1, bfz[cg][1], cz, 0, 0, 0);
                floatx4 chh = {cbh[cg], cbh[cg], cbh[cg], cbh[cg]};
                chh = __builtin_amdgcn_mfma_f32_16x16x32_bf16(a0, bfh[cg][0], chh, 0, 0, 0);
                chh = __builtin_amdgcn_mfma_f32_16x16x32_bf16(a1, bfh[cg][1], chh, 0, 0, 0);
#pragma unroll
                for (int r = 0; r < 4; ++r) {
                    int row = (grp << 4) + (quad << 2) + r;   // node within tile
                    float zc = fastrcp(1.0f + __expf(cz[r]));     // 1 - sigmoid
                    float th = 1.0f - 2.0f * fastrcp(1.0f + __expf(2.0f * chh[r]));
                    sH[row][col] = fmaxf(zc * th, 0.0f);
                }
            }
        }
        __syncthreads();
        {   // head: 16 threads per node, 16 channels each
            int nb = tid >> 4, g = tid & 15;
            float l0 = 0.f, l1 = 0.f, l2 = 0.f, l3 = 0.f;
#pragma unroll
            for (int ii = 0; ii < 16; ++ii) {
                int ch = g + 16 * ii;
                float hv = sH[nb][ch];
                l0 = fmaf(hv, sWo[0][ch], l0);
                l1 = fmaf(hv, sWo[1][ch], l1);
                l2 = fmaf(hv, sWo[2][ch], l2);
                l3 = fmaf(hv, sWo[3][ch], l3);
            }
#pragma unroll
            for (int off = 8; off > 0; off >>= 1) {
                l0 += __shfl_down(l0, off, 16);
                l1 += __shfl_down(l1, off, 16);
                l2 += __shfl_down(l2, off, 16);
                l3 += __shfl_down(l3, off, 16);
            }
            int node = node0 + nb;
            if (g == 0 && node < n) {
                float v0 = l0 + bo0, v1 = l1 + bo1, v2 = l2 + bo2, v3 = l3 + bo3;
                float mx = fmaxf(fmaxf(v0, v1), fmaxf(v2, v3));
                float e0 = __expf(v0 - mx), e1 = __expf(v1 - mx);
                float e2 = __expf(v2 - mx), e3 = __expf(v3 - mx);
                float inv = fastrcp(e0 + e1 + e2 + e3);
                float4 o;
                o.x = e0 * inv; o.y = e1 * inv; o.z = e2 * inv; o.w = e3 * inv;
                ((float4*)out)[node] = o;
            }
        }
        __syncthreads();
    }
}

extern "C" void kernel_launch(void* const* d_in, const int* in_sizes, int n_in,
                              void* d_out, int out_size, void* d_ws, size_t ws_size,
                              hipStream_t stream) {
    const float* x   = (const float*)d_in[0];
    const int*  eidx = (const int*)d_in[1];
    const float* Wz  = (const float*)d_in[2];
    const float* bz  = (const float*)d_in[3];
    // d_in[4]=Wr, d_in[5]=br : dead (H0 = 0)
    const float* Wh  = (const float*)d_in[6];
    const float* bh  = (const float*)d_in[7];
    const float* Lzw = (const float*)d_in[8];
    const float* Lzb = (const float*)d_in[9];
    // d_in[10]=Lrw, d_in[11]=Lrb : dead
    const float* Lhw = (const float*)d_in[12];
    const float* Lhb = (const float*)d_in[13];
    const float* Wo  = (const float*)d_in[14];
    const float* bo  = (const float*)d_in[15];
    float* out = (float*)d_out;

    int n = in_sizes[0] / 64;
    int E = in_sizes[1] / 2;
    const int* srcs = eidx;
    const int* dsts = eidx + E;
    int B = (n + NPB - 1) >> SHIFT;
    int nT = (E + TILE - 1) / TILE;

    size_t na = ((size_t)n + 3) & ~(size_t)3;
    size_t stageBytes = (((size_t)B * CAPB * 4) + 255) & ~(size_t)255;
    size_t aggBytes   = (((size_t)n * 64 * 2) + 255) & ~(size_t)255;

    char* ws = (char*)d_ws;
    int*   deg   = (int*)ws;    ws += na * 4;
    int*   gcur  = (int*)ws;    ws += BMAX * 4;
    int*   staging = (int*)ws;  ws += stageBytes;       // live through gather
    __half* xs   = (__half*)ws; ws += (size_t)n * 64 * 2;
    ushort* aggb = (ushort*)ws; ws += aggBytes;
    ushort* Mb   = (ushort*)ws; ws += 512 * 64 * 2;
    float* cb    = (float*)ws;  ws += 512 * 4;

    hipMemsetAsync(gcur, 0, BMAX * 4, stream);
    scatter_build_kernel<<<nT + MBBLK, 512, 0, stream>>>(srcs, dsts, gcur,
                                                         staging, E, B, nT,
                                                         Wz, bz, Wh, bh,
                                                         Lzw, Lzb, Lhw, Lhb,
                                                         Mb, cb);
    prep_kernel<<<B, 512, 0, stream>>>(staging, gcur, x, deg, xs, n, B);
    bucket_gather_kernel<<<B, 512, 0, stream>>>(staging, gcur, deg,
                                                xs, aggb, n, B);
    node_mfma_kernel<<<1024, 512, 0, stream>>>(aggb, Mb, cb, Wo, bo, out, n);
}

// Round 8
// 238.428 us; speedup vs baseline: 1.5404x; 1.0464x over previous
//
#include <hip/hip_runtime.h>
#include <hip/hip_fp16.h>

// TGCN forward, algebraically reduced (H0 = 0 => R/Wr dead, Z*H = 0):
//   deg[d] = #in-edges of d ; dinv = rsqrt(deg+1)
//   xs[s]  = fp16( x[s] * dinv[s] )
//   agg[d] = bf16( dinv[d] * ( sum_{e: dst=d} xs[src] + xs[d]*dinv[d] ) )
//   M = [Wz@Lzw_top | Wh@Lhw_top]  (64x512, bf16, MFMA B-layout), cb = bias fold
//   out = softmax(relu((1-Z)*Ht) @ Wo + bo)
//
// R1 -> R2: atomic scatter (2700us) -> CSR build + register gather.
// R3 -> R4: scatter write amp -> 2-level bucket sort (793 -> 455us).
// R7 -> R8: node GEMM -> mfma_f32_16x16x32_bf16 (412 -> off top-5).
// R14 -> R15: epilogue fp32 divides -> v_rcp_f32 (304 -> 275.7).
// R16: 9 -> 6 launches NEUTRAL: graph capture amortizes launches.
// R17: LDS ds_add_f32 per-edge accumulation DISASTER (1339us). Lesson:
//   LDS atomics only as occasional ops, never the per-element primitive.
// R18: deg via 3.2M scattered global atomics = 130us. Lesson: device-scope
//   scattered atomics are memory-side round trips; occasional only.
// R19: LDS-resident csr gather + LDS-histogram deg. 264.5us.
// R20: mega-fusion of node_mfma into gather FAILED (367): LDS-occupancy
//   crush + shfl/LDS-pipe head serialization. Reverted; gave attribution.
// R21: bucket-strided preallocation front-end. 252.1us.
// R22: LDS tile-sort + coalesced run copies; SHIFT 7 (window read once).
//   249.5us. bucket_gather 56.5 ~= its 150MB FETCH floor (random xs reads,
//   12.8MB table vs 4MB/XCD L2 — pinned without risky restructuring).
// R22 -> R23: the hidden ~193us middle. Bottom-up: prep ~18, node_mfma
//   ~12 => scatter_build ~45-55, and its build_m fold reads W[k*256+t]
//   with k=lane: 64 distinct lines PER SCALAR INSTRUCTION (130K line
//   touches/CU) — the fold, not the tile sort, likely bounds the fused
//   kernel. Fix 1: W via float4 (4x fewer instrs, 4 t-steps/line), same
//   fmaf order => bit-identical Mb/cb. Fix 2: run-copy in 16-lane groups
//   (runs avg 10.5 edges; 64-lane waves were 5/6 idle). Else identical.

#define SHIFT 7
#define NPB   128          // nodes per bucket (=1<<SHIFT)
#define BMAX  1024         // max buckets (n <= 131072 for 17-bit src packing)
#define TILE  8192         // edges per tile (scatter blocks)
#define EPT   16           // edges per thread in a tile (TILE/512)
#define MBBLK 64           // fused build_m blocks (512 j-cols / 8 per block)
#define CAPB  5120         // staging slots per bucket (mean 4096, sd 64)

typedef __attribute__((ext_vector_type(8))) short short8;
typedef __attribute__((ext_vector_type(4))) float floatx4;

__device__ __forceinline__ ushort f2b(float f) {   // fp32 -> bf16 RNE
    union { float f; unsigned u; } v; v.f = f;
    unsigned r = v.u + 0x7FFFu + ((v.u >> 16) & 1u);
    return (ushort)(r >> 16);
}

__device__ __forceinline__ float fastrcp(float x) {  // v_rcp_f32, ~1e-5 rel err
    return __builtin_amdgcn_rcpf(x);
}

// blocks [0,nT): per-tile: dsts -> regs + LDS hist; 1024-wide block scan;
//   block-granular global reserve; counting-sort tile into LDS `sorted`;
//   16-lane-group coalesced run copies into staging[b*CAPB + gbase + .].
// blocks [nT,nT+MBBLK): weight fold  Mb[j][k] = bf16(sum_t W[k][t]*L[t][j])
__global__ __launch_bounds__(512) void scatter_build_kernel(
    const int* __restrict__ srcs, const int* __restrict__ dsts,
    int* __restrict__ gcur, int* __restrict__ staging, int E, int B, int nT,
    const float* __restrict__ Wz, const float* __restrict__ bz,
    const float* __restrict__ Wh, const float* __restrict__ bh,
    const float* __restrict__ Lzw, const float* __restrict__ Lzb,
    const float* __restrict__ Lhw, const float* __restrict__ Lhb,
    ushort* __restrict__ Mb, float* __restrict__ cb) {
    __shared__ int cnt[BMAX];     // per-bucket tile count
    __shared__ int ssum[BMAX];    // inclusive scan of cnt
    __shared__ int gbase[BMAX];   // global reserved base
    __shared__ int cur[BMAX];     // LDS scatter cursor (local offset)
    __shared__ int sorted[TILE];  // tile payloads sorted by bucket (32KB)
    if (blockIdx.x < nT) {
        int tid = threadIdx.x;
        for (int i = tid; i < BMAX; i += 512) cnt[i] = 0;
        __syncthreads();
        int tile0 = blockIdx.x * TILE;
        int dreg[EPT];
#pragma unroll
        for (int j = 0; j < EPT; ++j) {
            int e = tile0 + j * 512 + tid;
            dreg[j] = (e < E) ? dsts[e] : -1;
            if (dreg[j] >= 0) atomicAdd(&cnt[((unsigned)dreg[j]) >> SHIFT], 1);
        }
        __syncthreads();
        // inclusive 1024-wide Hillis-Steele scan (2 elems/thread)
        {
            int i0 = tid, i1 = tid + 512;
            ssum[i0] = cnt[i0];
            ssum[i1] = cnt[i1];
            __syncthreads();
            for (int off = 1; off < BMAX; off <<= 1) {
                int t0 = (i0 >= off) ? ssum[i0 - off] : 0;
                int t1 = (i1 >= off) ? ssum[i1 - off] : 0;
                __syncthreads();
                ssum[i0] += t0;
                ssum[i1] += t1;
                __syncthreads();
            }
        }
        for (int i = tid; i < BMAX; i += 512) {
            int c = cnt[i];
            gbase[i] = (c > 0) ? atomicAdd(&gcur[i], c) : 0;   // reserve
            cur[i] = ssum[i] - c;                              // local base
        }
        __syncthreads();
        // counting-sort the tile into LDS (scattered stores -> LDS only)
#pragma unroll
        for (int j = 0; j < EPT; ++j) {
            int d = dreg[j];
            if (d >= 0) {
                int e = tile0 + j * 512 + tid;
                int s = srcs[e];
                int b = ((unsigned)d) >> SHIFT;
                int pos = atomicAdd(&cur[b], 1);
                sorted[pos] = ((d & (NPB - 1)) << 17) | s;
            }
        }
        __syncthreads();
        // 16-lane-group coalesced run copy to global staging (runs ~10.5)
        int grp = tid >> 4, l16 = tid & 15;     // 32 groups of 16 lanes
        for (int b = grp; b < B; b += 32) {
            int c = cnt[b];
            if (c == 0) continue;
            int lb = ssum[b] - c;
            int gb = gbase[b];
            size_t gp = (size_t)b * CAPB + gb;
            for (int j = l16; j < c; j += 16)
                if (gb + j < CAPB) staging[gp + j] = sorted[lb + j];
        }
    } else {
        int j = (blockIdx.x - nT) * 8 + (threadIdx.x >> 6);   // 0..511
        int k = threadIdx.x & 63;                             // 0..63
        int which = j >> 8;
        int jj = j & 255;
        const float* W  = which ? Wh  : Wz;
        const float* bv = which ? bh  : bz;
        const float* L  = which ? Lhw : Lzw;   // [512,256]; rows 0..255 (H0=0)
        const float* Lb = which ? Lhb : Lzb;
        // W row via float4: 4 t-steps per line touch (was 64 lines/scalar
        // instr). Same fmaf chain order -> bit-identical to scalar version.
        const float4* Wr = (const float4*)(W + k * 256);
        float acc = 0.f;
        for (int t4 = 0; t4 < 64; ++t4) {
            float4 wv = Wr[t4];
            int t = t4 * 4;
            acc = fmaf(wv.x, L[(t + 0) * 256 + jj], acc);
            acc = fmaf(wv.y, L[(t + 1) * 256 + jj], acc);
            acc = fmaf(wv.z, L[(t + 2) * 256 + jj], acc);
            acc = fmaf(wv.w, L[(t + 3) * 256 + jj], acc);
        }
        Mb[j * 64 + k] = f2b(acc);
        if (k == 0) {
            float a = 0.f;
            for (int t = 0; t < 256; ++t) a = fmaf(bv[t], L[t * 256 + jj], a);
            cb[j] = a + Lb[jj];
        }
    }
}

// one block per 128-node bucket: deg counted from the bucket's staging
// window via LDS histogram atomics, deg written coalesced; then the
// bucket's xs rows: xs[s][c] = fp16(x[s][c]*dinv[s]) (dinv in LDS only).
__global__ __launch_bounds__(512) void prep_kernel(const int* __restrict__ staging,
                                                   const int* __restrict__ gcur,
                                                   const float* __restrict__ x,
                                                   int* __restrict__ deg,
                                                   __half* __restrict__ xs,
                                                   int n, int B) {
    int b = blockIdx.x;
    int tid = threadIdx.x;
    __shared__ int nd[NPB];
    __shared__ float sdinv[NPB];
    if (tid < NPB) nd[tid] = 0;
    __syncthreads();
    int count = gcur[b];
    if (count > CAPB) count = CAPB;
    size_t base = (size_t)b * CAPB;
    for (int i = tid; i < count; i += 512)
        atomicAdd(&nd[staging[base + i] >> 17], 1);
    __syncthreads();
    if (tid < NPB) {
        int dg = nd[tid];
        float dn = rsqrtf((float)dg + 1.0f);
        sdinv[tid] = dn;
        int node = (b << SHIFT) + tid;
        if (node < n) deg[node] = dg;
    }
    __syncthreads();
    int nbase = b << SHIFT;
    for (int i2 = tid; i2 < NPB * 16; i2 += 512) {
        int nl = i2 >> 4;
        int node = nbase + nl;
        if (node < n) {
            float dn = sdinv[nl];
            size_t gi = (size_t)node * 16 + (i2 & 15);
            float4 vx = ((const float4*)x)[gi];
            __half2 a = __floats2half2_rn(vx.x * dn, vx.y * dn);
            __half2 c = __floats2half2_rn(vx.z * dn, vx.w * dn);
            ((__half2*)xs)[gi * 2 + 0] = a;
            ((__half2*)xs)[gi * 2 + 1] = c;
        }
    }
}

// one block per 128-node bucket. Counting sort INTO LDS (window read once):
// deg row -> scan -> cursor scatter into csrl[CAPB]. Then register gather:
// wave w owns 16 nodes; lane = (edge_group 0..7) x (16B chunk 0..7); edge
// indices read via conflict-free LDS broadcast. fp16 accumulate, bf16 out.
__global__ __launch_bounds__(512) void bucket_gather_kernel(
    const int* __restrict__ staging,
    const int* __restrict__ gcur,
    const int* __restrict__ deg,
    const __half* __restrict__ xs,
    ushort* __restrict__ aggb, int n, int B) {
    int b   = blockIdx.x;
    int tid = threadIdx.x;
    __shared__ int   csrl[CAPB];
    __shared__ int   sstart[NPB];
    __shared__ int   ncur[NPB];
    __shared__ int   sdeg[NPB];
    __shared__ int   ssc[NPB];
    __shared__ float sdinv[NPB];
    int node0 = b << SHIFT;
    int count = gcur[b];
    if (count > CAPB) count = CAPB;
    size_t base = (size_t)b * CAPB;
    if (tid < NPB) {
        int nodeid = node0 + tid;
        int dg = (nodeid < n) ? deg[nodeid] : 0;
        sdeg[tid] = dg;
        ssc[tid]  = dg;
        sdinv[tid] = rsqrtf((float)dg + 1.0f);
    }
    __syncthreads();
    for (int off = 1; off < NPB; off <<= 1) {
        int t = 0;
        if (tid < NPB && tid >= off) t = ssc[tid - off];
        __syncthreads();
        if (tid < NPB) ssc[tid] += t;
        __syncthreads();
    }
    if (tid < NPB) {
        int excl = ssc[tid] - sdeg[tid];
        sstart[tid] = excl;
        ncur[tid]   = excl;
    }
    __syncthreads();
    // counting-sort scatter: one coalesced staging pass, LDS stores only
    for (int i = tid; i < count; i += 512) {
        int p = staging[base + i];
        int pos = atomicAdd(&ncur[p >> 17], 1);
        if (pos < CAPB) csrl[pos] = p & 0x1FFFF;
    }
    __syncthreads();
    // register gather (identical numerics to the R16 gather kernel)
    int wv = tid >> 6, lane = tid & 63;
    int eg = lane >> 3;      // edge group 0..7
    int c  = lane & 7;       // 16B chunk (8 halfs)
    for (int t16 = 0; t16 < 16; ++t16) {
        int nl   = (wv << 4) + t16;
        int node = node0 + nl;
        int s0 = sstart[nl];
        int d  = sdeg[nl];
        __half2 hz = __float2half2_rn(0.f);
        __half2 hacc[4] = {hz, hz, hz, hz};
        int full = d & ~15;
        for (int be = 0; be < full; be += 16) {
            int qb = s0 + be;
            if (qb > CAPB - 16) qb = CAPB - 16;    // safety clamp, never binds
            int i0 = csrl[qb + eg];
            int i1 = csrl[qb + 8 + eg];
            union { uint4 u; __half2 h[4]; } p0, p1;
            p0.u = *(const uint4*)(xs + (size_t)i0 * 64 + c * 8);
            p1.u = *(const uint4*)(xs + (size_t)i1 * 64 + c * 8);
#pragma unroll
            for (int t = 0; t < 4; ++t) hacc[t] = __hadd2(hacc[t], p0.h[t]);
#pragma unroll
            for (int t = 0; t < 4; ++t) hacc[t] = __hadd2(hacc[t], p1.h[t]);
        }
        if (full < d) {   // ragged tail (< 16 edges)
            int e0 = full + eg;
            int e1 = full + 8 + eg;
            int q0 = s0 + (e0 < d ? e0 : d - 1);
            int q1 = s0 + (e1 < d ? e1 : d - 1);
            if (q0 > CAPB - 1) q0 = CAPB - 1;
            if (q1 > CAPB - 1) q1 = CAPB - 1;
            int i0 = csrl[q0];
            int i1 = csrl[q1];
            union { uint4 u; __half2 h[4]; } p0, p1;
            p0.u = *(const uint4*)(xs + (size_t)i0 * 64 + c * 8);
            p1.u = *(const uint4*)(xs + (size_t)i1 * 64 + c * 8);
            if (e0 >= d) p0.u = make_uint4(0u, 0u, 0u, 0u);
            if (e1 >= d) p1.u = make_uint4(0u, 0u, 0u, 0u);
#pragma unroll
            for (int t = 0; t < 4; ++t) hacc[t] = __hadd2(hacc[t], p0.h[t]);
#pragma unroll
            for (int t = 0; t < 4; ++t) hacc[t] = __hadd2(hacc[t], p1.h[t]);
        }
        // packed cross-lane reduce of the 8 edge groups down to eg==0
#pragma unroll
        for (int off = 32; off >= 8; off >>= 1) {
#pragma unroll
            for (int t = 0; t < 4; ++t) {
                union { __half2 h; int i; } u;
                u.h = hacc[t];
                u.i = __shfl_down(u.i, off);
                hacc[t] = __hadd2(hacc[t], u.h);
            }
        }
        if (eg == 0 && node < n) {
            float dn = sdinv[nl];
            union { uint4 u; __half2 h[4]; } p;
            p.u = *(const uint4*)(xs + (size_t)node * 64 + c * 8);
            uint4 o;
            unsigned* ow = (unsigned*)&o;
#pragma unroll
            for (int t = 0; t < 4; ++t) {
                float2 a = __half22float2(hacc[t]);
                float2 f = __half22float2(p.h[t]);
                float v0 = dn * fmaf(f.x, dn, a.x);
                float v1 = dn * fmaf(f.y, dn, a.y);
                ow[t] = (unsigned)f2b(v0) | ((unsigned)f2b(v1) << 16);
            }
            ((uint4*)(aggb + (size_t)node * 64))[c] = o;
        }
    }
}

// 512 threads = 8 waves. Wave w owns cols w*32..w*32+31 for BOTH gates
// (z and ht meet in-register, h=relu((1-z)*ht) -> one h-plane in LDS).
__global__ __launch_bounds__(512) void node_mfma_kernel(
    const ushort* __restrict__ aggb,   // [n][64] bf16
    const ushort* __restrict__ Mb,     // [512][64] bf16 (B layout)
    const float* __restrict__ cb,      // [512]
    const float* __restrict__ Wo, const float* __restrict__ bo,
    float* __restrict__ out, int n) {
    int tid  = threadIdx.x;
    int w    = tid >> 6;
    int lane = tid & 63;
    int nidx = lane & 15;
    int quad = lane >> 4;
    short8 bfz[2][2], bfh[2][2];
    float cbz[2], cbh[2];
#pragma unroll
    for (int cg = 0; cg < 2; ++cg) {
        int colZ = (w << 5) + (cg << 4) + nidx;
        int colH = 256 + colZ;
#pragma unroll
        for (int s = 0; s < 2; ++s) {
            bfz[cg][s] = *(const short8*)(Mb + colZ * 64 + s * 32 + quad * 8);
            bfh[cg][s] = *(const short8*)(Mb + colH * 64 + s * 32 + quad * 8);
        }
        cbz[cg] = cb[colZ];
        cbh[cg] = cb[colH];
    }
    __shared__ float sH[32][260];    // 33 KB h-plane (260 pad: 2-way on stores)
    __shared__ float sWo[4][256];
    if (tid < 256) {
#pragma unroll
        for (int o = 0; o < 4; ++o) sWo[o][tid] = Wo[tid * 4 + o];
    }
    float bo0 = bo[0], bo1 = bo[1], bo2 = bo[2], bo3 = bo[3];
    int ntiles = (n + 31) >> 5;
    for (int tile = blockIdx.x; tile < ntiles; tile += gridDim.x) {
        int node0 = tile << 5;
        int nA0 = node0 + nidx;
        int nA1 = node0 + 16 + nidx;
        if (nA0 >= n) nA0 = n - 1;   // clamp; stores are guarded
        if (nA1 >= n) nA1 = n - 1;
        const ushort* ar0 = aggb + (size_t)nA0 * 64;
        const ushort* ar1 = aggb + (size_t)nA1 * 64;
        short8 a00 = *(const short8*)(ar0 + quad * 8);
        short8 a01 = *(const short8*)(ar0 + 32 + quad * 8);
        short8 a10 = *(const short8*)(ar1 + quad * 8);
        short8 a11 = *(const short8*)(ar1 + 32 + quad * 8);
#pragma unroll
        for (int cg = 0; cg < 2; ++cg) {
            int col = (w << 5) + (cg << 4) + nidx;
#pragma unroll
            for (int grp = 0; grp < 2; ++grp) {
                short8 a0 = grp ? a10 : a00;
                short8 a1 = grp ? a11 : a01;
                floatx4 cz = {cbz[cg], cbz[cg], cbz[cg], cbz[cg]};
                cz = __builtin_amdgcn_mfma_f32_16x16x32_bf16(a0, bfz[cg][0], cz, 0, 0, 0);
                cz = __builtin_amdgcn_mfma_f32_16x16x32_bf16(a1, bfz[cg][1], cz, 0, 0, 0);
                floatx4 chh = {cbh[cg], cbh[cg], cbh[cg], cbh[cg]};
                chh = __builtin_amdgcn_mfma_f32_16x16x32_bf16(a0, bfh[cg][0], chh, 0, 0, 0);
                chh = __builtin_amdgcn_mfma_f32_16x16x32_bf16(a1, bfh[cg][1], chh, 0, 0, 0);
#pragma unroll
                for (int r = 0; r < 4; ++r) {
                    int row = (grp << 4) + (quad << 2) + r;   // node within tile
                    float zc = fastrcp(1.0f + __expf(cz[r]));     // 1 - sigmoid
                    float th = 1.0f - 2.0f * fastrcp(1.0f + __expf(2.0f * chh[r]));
                    sH[row][col] = fmaxf(zc * th, 0.0f);
                }
            }
        }
        __syncthreads();
        {   // head: 16 threads per node, 16 channels each
            int nb = tid >> 4, g = tid & 15;
            float l0 = 0.f, l1 = 0.f, l2 = 0.f, l3 = 0.f;
#pragma unroll
            for (int ii = 0; ii < 16; ++ii) {
                int ch = g + 16 * ii;
                float hv = sH[nb][ch];
                l0 = fmaf(hv, sWo[0][ch], l0);
                l1 = fmaf(hv, sWo[1][ch], l1);
                l2 = fmaf(hv, sWo[2][ch], l2);
                l3 = fmaf(hv, sWo[3][ch], l3);
            }
#pragma unroll
            for (int off = 8; off > 0; off >>= 1) {
                l0 += __shfl_down(l0, off, 16);
                l1 += __shfl_down(l1, off, 16);
                l2 += __shfl_down(l2, off, 16);
                l3 += __shfl_down(l3, off, 16);
            }
            int node = node0 + nb;
            if (g == 0 && node < n) {
                float v0 = l0 + bo0, v1 = l1 + bo1, v2 = l2 + bo2, v3 = l3 + bo3;
                float mx = fmaxf(fmaxf(v0, v1), fmaxf(v2, v3));
                float e0 = __expf(v0 - mx), e1 = __expf(v1 - mx);
                float e2 = __expf(v2 - mx), e3 = __expf(v3 - mx);
                float inv = fastrcp(e0 + e1 + e2 + e3);
                float4 o;
                o.x = e0 * inv; o.y = e1 * inv; o.z = e2 * inv; o.w = e3 * inv;
                ((float4*)out)[node] = o;
            }
        }
        __syncthreads();
    }
}

extern "C" void kernel_launch(void* const* d_in, const int* in_sizes, int n_in,
                              void* d_out, int out_size, void* d_ws, size_t ws_size,
                              hipStream_t stream) {
    const float* x   = (const float*)d_in[0];
    const int*  eidx = (const int*)d_in[1];
    const float* Wz  = (const float*)d_in[2];
    const float* bz  = (const float*)d_in[3];
    // d_in[4]=Wr, d_in[5]=br : dead (H0 = 0)
    const float* Wh  = (const float*)d_in[6];
    const float* bh  = (const float*)d_in[7];
    const float* Lzw = (const float*)d_in[8];
    const float* Lzb = (const float*)d_in[9];
    // d_in[10]=Lrw, d_in[11]=Lrb : dead
    const float* Lhw = (const float*)d_in[12];
    const float* Lhb = (const float*)d_in[13];
    const float* Wo  = (const float*)d_in[14];
    const float* bo  = (const float*)d_in[15];
    float* out = (float*)d_out;

    int n = in_sizes[0] / 64;
    int E = in_sizes[1] / 2;
    const int* srcs = eidx;
    const int* dsts = eidx + E;
    int B = (n + NPB - 1) >> SHIFT;
    int nT = (E + TILE - 1) / TILE;

    size_t na = ((size_t)n + 3) & ~(size_t)3;
    size_t stageBytes = (((size_t)B * CAPB * 4) + 255) & ~(size_t)255;
    size_t aggBytes   = (((size_t)n * 64 * 2) + 255) & ~(size_t)255;

    char* ws = (char*)d_ws;
    int*   deg   = (int*)ws;    ws += na * 4;
    int*   gcur  = (int*)ws;    ws += BMAX * 4;
    int*   staging = (int*)ws;  ws += stageBytes;       // live through gather
    __half* xs   = (__half*)ws; ws += (size_t)n * 64 * 2;
    ushort* aggb = (ushort*)ws; ws += aggBytes;
    ushort* Mb   = (ushort*)ws; ws += 512 * 64 * 2;
    float* cb    = (float*)ws;  ws += 512 * 4;

    hipMemsetAsync(gcur, 0, BMAX * 4, stream);
    scatter_build_kernel<<<nT + MBBLK, 512, 0, stream>>>(srcs, dsts, gcur,
                                                         staging, E, B, nT,
                                                         Wz, bz, Wh, bh,
                                                         Lzw, Lzb, Lhw, Lhb,
                                                         Mb, cb);
    prep_kernel<<<B, 512, 0, stream>>>(staging, gcur, x, deg, xs, n, B);
    bucket_gather_kernel<<<B, 512, 0, stream>>>(staging, gcur, deg,
                                                xs, aggb, n, B);
    node_mfma_kernel<<<1024, 512, 0, stream>>>(aggb, Mb, cb, Wo, bo, out, n);
}